// Round 2
// baseline (612.315 us; speedup 1.0000x reference)
//
#include <hip/hip_runtime.h>
#include <hip/hip_bf16.h>

typedef short bf16x8 __attribute__((ext_vector_type(8)));
typedef float f32x4 __attribute__((ext_vector_type(4)));

#define MFMA16(a,b,c) __builtin_amdgcn_mfma_f32_16x16x32_bf16(a,b,c,0,0,0)

__device__ __forceinline__ unsigned short f2bf(float x){
    unsigned int u = __float_as_uint(x);
    u += 0x7fffu + ((u >> 16) & 1u);
    return (unsigned short)(u >> 16);
}
__device__ __forceinline__ float bf2f(unsigned short h){
    return __uint_as_float(((unsigned int)h) << 16);
}
__device__ __forceinline__ unsigned int f2bf2(float a, float b){
    return ((unsigned int)f2bf(a)) | (((unsigned int)f2bf(b)) << 16);
}

// ---------------------------------------------------------------------------
// GEMM: C[4096,768] = A[4096,768] @ W[768,768]^T + bias
// Tile M=128, N=64, Kstep=32. 256 threads (4 waves), wave w owns rows w*32..+31.
// z = 0,1: q/k -> head-major bf16 [B,H,S,HD]; z = 2: v -> transposed [B,H,HD,S].
// ---------------------------------------------------------------------------
__global__ __launch_bounds__(256) void gemm_proj(
    const float* __restrict__ Aq, const float* __restrict__ Ak, const float* __restrict__ Av,
    const float* __restrict__ W, const float* __restrict__ bias,
    unsigned short* __restrict__ qh, unsigned short* __restrict__ kh,
    unsigned short* __restrict__ vt)
{
    __shared__ unsigned short As[128][56];  // stride 56 el = 112B (16B-aligned, 2-way banks)
    __shared__ unsigned short Bs[64][56];
    const int z = blockIdx.z;
    const float* A = (z == 0) ? Aq : ((z == 1) ? Ak : Av);
    const int m0 = blockIdx.x * 128, n0 = blockIdx.y * 64;
    const int tid = threadIdx.x;
    const int w = tid >> 6, lane = tid & 63, col15 = lane & 15, quad = lane >> 4;

    f32x4 c[2][4];
#pragma unroll
    for (int ms = 0; ms < 2; ++ms)
#pragma unroll
        for (int ns = 0; ns < 4; ++ns) c[ms][ns] = (f32x4){0.f, 0.f, 0.f, 0.f};

    const int arow = tid >> 1, acol = (tid & 1) * 16;
    const int brow = tid >> 2, bcol = (tid & 3) * 8;

    for (int k0 = 0; k0 < 768; k0 += 32) {
        __syncthreads();
        {   // stage A (f32 -> bf16), 16 el/thread
            const float* s = A + (size_t)(m0 + arow) * 768 + k0 + acol;
            float4 f0 = ((const float4*)s)[0], f1 = ((const float4*)s)[1];
            float4 f2 = ((const float4*)s)[2], f3 = ((const float4*)s)[3];
            uint4 w0 = make_uint4(f2bf2(f0.x, f0.y), f2bf2(f0.z, f0.w),
                                  f2bf2(f1.x, f1.y), f2bf2(f1.z, f1.w));
            uint4 w1 = make_uint4(f2bf2(f2.x, f2.y), f2bf2(f2.z, f2.w),
                                  f2bf2(f3.x, f3.y), f2bf2(f3.z, f3.w));
            *(uint4*)&As[arow][acol] = w0;
            *(uint4*)&As[arow][acol + 8] = w1;
        }
        {   // stage B (W rows n0..n0+63), 8 el/thread
            const float* s = W + (size_t)(n0 + brow) * 768 + k0 + bcol;
            float4 f0 = ((const float4*)s)[0], f1 = ((const float4*)s)[1];
            uint4 w0 = make_uint4(f2bf2(f0.x, f0.y), f2bf2(f0.z, f0.w),
                                  f2bf2(f1.x, f1.y), f2bf2(f1.z, f1.w));
            *(uint4*)&Bs[brow][bcol] = w0;
        }
        __syncthreads();
        bf16x8 af0 = *(const bf16x8*)&As[w * 32 + col15][quad * 8];
        bf16x8 af1 = *(const bf16x8*)&As[w * 32 + 16 + col15][quad * 8];
        bf16x8 b0 = *(const bf16x8*)&Bs[col15][quad * 8];
        bf16x8 b1 = *(const bf16x8*)&Bs[16 + col15][quad * 8];
        bf16x8 b2 = *(const bf16x8*)&Bs[32 + col15][quad * 8];
        bf16x8 b3 = *(const bf16x8*)&Bs[48 + col15][quad * 8];
        c[0][0] = MFMA16(af0, b0, c[0][0]);
        c[0][1] = MFMA16(af0, b1, c[0][1]);
        c[0][2] = MFMA16(af0, b2, c[0][2]);
        c[0][3] = MFMA16(af0, b3, c[0][3]);
        c[1][0] = MFMA16(af1, b0, c[1][0]);
        c[1][1] = MFMA16(af1, b1, c[1][1]);
        c[1][2] = MFMA16(af1, b2, c[1][2]);
        c[1][3] = MFMA16(af1, b3, c[1][3]);
    }

#pragma unroll
    for (int ms = 0; ms < 2; ++ms)
#pragma unroll
        for (int ns = 0; ns < 4; ++ns) {
            const int colg = n0 + ns * 16 + col15;
            const float bv = bias[colg];
            const int h = colg >> 6, d = colg & 63;
#pragma unroll
            for (int e = 0; e < 4; ++e) {
                const int m = m0 + w * 32 + ms * 16 + quad * 4 + e;
                const int b = m >> 10, sIdx = m & 1023;
                const float val = c[ms][ns][e] + bv;
                if (z == 2)
                    vt[((b * 12 + h) * 64 + d) * 1024 + sIdx] = f2bf(val);
                else {
                    unsigned short* dst = (z == 0) ? qh : kh;
                    dst[((b * 12 + h) * 1024 + sIdx) * 64 + d] = f2bf(val);
                }
            }
        }
}

// ---------------------------------------------------------------------------
// Final GEMM: out[4096,768] = Abf[4096,768](bf16) @ Wf^T + bf   (fp32 out)
// ---------------------------------------------------------------------------
__global__ __launch_bounds__(256) void gemm_out(
    const unsigned short* __restrict__ Abf, const float* __restrict__ W,
    const float* __restrict__ bias, float* __restrict__ out)
{
    __shared__ unsigned short As[128][56];
    __shared__ unsigned short Bs[64][56];
    const int m0 = blockIdx.x * 128, n0 = blockIdx.y * 64;
    const int tid = threadIdx.x;
    const int w = tid >> 6, lane = tid & 63, col15 = lane & 15, quad = lane >> 4;

    f32x4 c[2][4];
#pragma unroll
    for (int ms = 0; ms < 2; ++ms)
#pragma unroll
        for (int ns = 0; ns < 4; ++ns) c[ms][ns] = (f32x4){0.f, 0.f, 0.f, 0.f};

    const int arow = tid >> 1, acol = (tid & 1) * 16;
    const int brow = tid >> 2, bcol = (tid & 3) * 8;

    for (int k0 = 0; k0 < 768; k0 += 32) {
        __syncthreads();
        {
            const unsigned short* s = Abf + (size_t)(m0 + arow) * 768 + k0 + acol;
            *(bf16x8*)&As[arow][acol] = *(const bf16x8*)s;
            *(bf16x8*)&As[arow][acol + 8] = *(const bf16x8*)(s + 8);
        }
        {
            const float* s = W + (size_t)(n0 + brow) * 768 + k0 + bcol;
            float4 f0 = ((const float4*)s)[0], f1 = ((const float4*)s)[1];
            uint4 w0 = make_uint4(f2bf2(f0.x, f0.y), f2bf2(f0.z, f0.w),
                                  f2bf2(f1.x, f1.y), f2bf2(f1.z, f1.w));
            *(uint4*)&Bs[brow][bcol] = w0;
        }
        __syncthreads();
        bf16x8 af0 = *(const bf16x8*)&As[w * 32 + col15][quad * 8];
        bf16x8 af1 = *(const bf16x8*)&As[w * 32 + 16 + col15][quad * 8];
        bf16x8 b0 = *(const bf16x8*)&Bs[col15][quad * 8];
        bf16x8 b1 = *(const bf16x8*)&Bs[16 + col15][quad * 8];
        bf16x8 b2 = *(const bf16x8*)&Bs[32 + col15][quad * 8];
        bf16x8 b3 = *(const bf16x8*)&Bs[48 + col15][quad * 8];
        c[0][0] = MFMA16(af0, b0, c[0][0]);
        c[0][1] = MFMA16(af0, b1, c[0][1]);
        c[0][2] = MFMA16(af0, b2, c[0][2]);
        c[0][3] = MFMA16(af0, b3, c[0][3]);
        c[1][0] = MFMA16(af1, b0, c[1][0]);
        c[1][1] = MFMA16(af1, b1, c[1][1]);
        c[1][2] = MFMA16(af1, b2, c[1][2]);
        c[1][3] = MFMA16(af1, b3, c[1][3]);
    }

#pragma unroll
    for (int ms = 0; ms < 2; ++ms)
#pragma unroll
        for (int ns = 0; ns < 4; ++ns) {
            const int colg = n0 + ns * 16 + col15;
            const float bv = bias[colg];
#pragma unroll
            for (int e = 0; e < 4; ++e) {
                const int m = m0 + w * 32 + ms * 16 + quad * 4 + e;
                out[(size_t)m * 768 + colg] = c[ms][ns][e] + bv;
            }
        }
}

// ---------------------------------------------------------------------------
// colsum over keys of V (transposed layout): cs[b,g,d] = sum_s vt[b,g,d,s]
// ---------------------------------------------------------------------------
__global__ __launch_bounds__(256) void colsum_k(
    const unsigned short* __restrict__ vt, float* __restrict__ cs)
{
    const int row = blockIdx.x * 4 + (threadIdx.x >> 6);  // 0..3071
    const int lane = threadIdx.x & 63;
    const unsigned short* p = vt + (size_t)row * 1024;
    float s = 0.f;
    for (int i = lane; i < 1024; i += 64) s += bf2f(p[i]);
    s += __shfl_xor(s, 1, 64);  s += __shfl_xor(s, 2, 64);
    s += __shfl_xor(s, 4, 64);  s += __shfl_xor(s, 8, 64);
    s += __shfl_xor(s, 16, 64); s += __shfl_xor(s, 32, 64);
    if (lane == 0) cs[row] = s;
}

// ---------------------------------------------------------------------------
// Attention pass 1: per (ks,qt,b) compute partial row-sums of exp(mixed logits)
// Block = 256 thr (4 waves); wave w handles 16-key tiles t = w, w+4, ... (<32).
// ---------------------------------------------------------------------------
__global__ __launch_bounds__(256) void attn_pass1(
    const unsigned short* __restrict__ qh, const unsigned short* __restrict__ kh,
    const float* __restrict__ Wl, const float* __restrict__ bl,
    float* __restrict__ l_part)
{
    const int ks = blockIdx.x, qt = blockIdx.y, b = blockIdx.z;
    const int tid = threadIdx.x, w = tid >> 6, lane = tid & 63;
    const int col15 = lane & 15, quad = lane >> 4;
    const int q0 = qt * 16;
    __shared__ float lred[4][12][16];

    float lsum[12][4];
#pragma unroll
    for (int g = 0; g < 12; ++g)
#pragma unroll
        for (int e = 0; e < 4; ++e) lsum[g][e] = 0.f;

    const unsigned short* qbase = qh + (size_t)(b * 12) * 1024 * 64;
    const unsigned short* kbase = kh + (size_t)(b * 12) * 1024 * 64;

    for (int t = w; t < 32; t += 4) {
        const int kb = ks * 512 + t * 16;
        f32x4 sf[12];
#pragma unroll
        for (int h = 0; h < 12; ++h) {
            const unsigned short* qp = qbase + ((size_t)h * 1024 + q0 + col15) * 64 + quad * 8;
            const unsigned short* kp = kbase + ((size_t)h * 1024 + kb + col15) * 64 + quad * 8;
            bf16x8 qf0 = *(const bf16x8*)qp;
            bf16x8 qf1 = *(const bf16x8*)(qp + 32);
            bf16x8 kf0 = *(const bf16x8*)kp;
            bf16x8 kf1 = *(const bf16x8*)(kp + 32);
            f32x4 acc = (f32x4){0.f, 0.f, 0.f, 0.f};
            acc = MFMA16(qf0, kf0, acc);
            acc = MFMA16(qf1, kf1, acc);
            sf[h] = acc;
        }
#pragma unroll
        for (int g = 0; g < 12; ++g) {
            float m0 = bl[g], m1 = bl[g], m2 = bl[g], m3 = bl[g];
#pragma unroll
            for (int h = 0; h < 12; ++h) {
                const float wv = 0.125f * Wl[g * 12 + h];
                m0 += wv * sf[h][0]; m1 += wv * sf[h][1];
                m2 += wv * sf[h][2]; m3 += wv * sf[h][3];
            }
            lsum[g][0] += __expf(m0); lsum[g][1] += __expf(m1);
            lsum[g][2] += __expf(m2); lsum[g][3] += __expf(m3);
        }
    }

#pragma unroll
    for (int g = 0; g < 12; ++g)
#pragma unroll
        for (int e = 0; e < 4; ++e) {
            float v = lsum[g][e];
            v += __shfl_xor(v, 1, 64); v += __shfl_xor(v, 2, 64);
            v += __shfl_xor(v, 4, 64); v += __shfl_xor(v, 8, 64);
            if (col15 == 0) lred[w][g][quad * 4 + e] = v;
        }
    __syncthreads();
    if (tid < 192) {
        const int g = tid >> 4, r = tid & 15;
        const float tot = lred[0][g][r] + lred[1][g][r] + lred[2][g][r] + lred[3][g][r];
        l_part[((size_t)(ks * 4 + b) * 12 + g) * 1024 + q0 + r] = tot;
    }
}

// ---------------------------------------------------------------------------
// Attention pass 2: recompute S, normalize with l, post-mix (Wp), PV via MFMA.
// Phase A: each wave computes its 16-key strip of the 64-key tile for all 12
// heads, writes post-mixed P (bf16) to LDS. Phase B: wave w handles heads
// g2 = 3w..3w+2, PV-MFMA from LDS P and global V^T. Writes fp32 partials.
// ---------------------------------------------------------------------------
__global__ __launch_bounds__(256) void attn_pass2(
    const unsigned short* __restrict__ qh, const unsigned short* __restrict__ kh,
    const unsigned short* __restrict__ vt,
    const float* __restrict__ Wl, const float* __restrict__ bl,
    const float* __restrict__ Wp,
    const float* __restrict__ l_part, float* __restrict__ attn_part)
{
    const int ks = blockIdx.x, qt = blockIdx.y, b = blockIdx.z;
    const int tid = threadIdx.x, w = tid >> 6, lane = tid & 63;
    const int col15 = lane & 15, quad = lane >> 4;
    const int q0 = qt * 16;

    __shared__ unsigned short Pt[12][16][72];  // [g2][q][k64 padded]
    __shared__ float linv[12][16];

    if (tid < 192) {
        const int g = tid >> 4, r = tid & 15;
        const float s = l_part[((size_t)(0 + b) * 12 + g) * 1024 + q0 + r]
                      + l_part[((size_t)(4 + b) * 12 + g) * 1024 + q0 + r];
        linv[g][r] = 1.f / s;
    }
    __syncthreads();

    const unsigned short* qbase = qh + (size_t)(b * 12) * 1024 * 64;
    const unsigned short* kbase = kh + (size_t)(b * 12) * 1024 * 64;

    f32x4 of[3][4];
#pragma unroll
    for (int i = 0; i < 3; ++i)
#pragma unroll
        for (int ds = 0; ds < 4; ++ds) of[i][ds] = (f32x4){0.f, 0.f, 0.f, 0.f};

    for (int pt = 0; pt < 8; ++pt) {
        const int kb64 = ks * 512 + pt * 64;
        const int kb = kb64 + w * 16;

        f32x4 sf[12];
#pragma unroll
        for (int h = 0; h < 12; ++h) {
            const unsigned short* qp = qbase + ((size_t)h * 1024 + q0 + col15) * 64 + quad * 8;
            const unsigned short* kp = kbase + ((size_t)h * 1024 + kb + col15) * 64 + quad * 8;
            bf16x8 qf0 = *(const bf16x8*)qp;
            bf16x8 qf1 = *(const bf16x8*)(qp + 32);
            bf16x8 kf0 = *(const bf16x8*)kp;
            bf16x8 kf1 = *(const bf16x8*)(kp + 32);
            f32x4 acc = (f32x4){0.f, 0.f, 0.f, 0.f};
            acc = MFMA16(qf0, kf0, acc);
            acc = MFMA16(qf1, kf1, acc);
            sf[h] = acc;
        }

        float p[12][4];
#pragma unroll
        for (int g = 0; g < 12; ++g) {
            float m0 = bl[g], m1 = bl[g], m2 = bl[g], m3 = bl[g];
#pragma unroll
            for (int h = 0; h < 12; ++h) {
                const float wv = 0.125f * Wl[g * 12 + h];
                m0 += wv * sf[h][0]; m1 += wv * sf[h][1];
                m2 += wv * sf[h][2]; m3 += wv * sf[h][3];
            }
            p[g][0] = __expf(m0) * linv[g][quad * 4 + 0];
            p[g][1] = __expf(m1) * linv[g][quad * 4 + 1];
            p[g][2] = __expf(m2) * linv[g][quad * 4 + 2];
            p[g][3] = __expf(m3) * linv[g][quad * 4 + 3];
        }
#pragma unroll
        for (int g2 = 0; g2 < 12; ++g2) {
            float a0 = 0.f, a1 = 0.f, a2 = 0.f, a3 = 0.f;
#pragma unroll
            for (int g = 0; g < 12; ++g) {
                const float wv = Wp[g2 * 12 + g];
                a0 += wv * p[g][0]; a1 += wv * p[g][1];
                a2 += wv * p[g][2]; a3 += wv * p[g][3];
            }
            Pt[g2][quad * 4 + 0][w * 16 + col15] = f2bf(a0);
            Pt[g2][quad * 4 + 1][w * 16 + col15] = f2bf(a1);
            Pt[g2][quad * 4 + 2][w * 16 + col15] = f2bf(a2);
            Pt[g2][quad * 4 + 3][w * 16 + col15] = f2bf(a3);
        }
        __syncthreads();

#pragma unroll
        for (int i = 0; i < 3; ++i) {
            const int g2 = w * 3 + i;
            const unsigned short* vb = vt + (size_t)((b * 12 + g2) * 64) * 1024;
#pragma unroll
            for (int ksub = 0; ksub < 2; ++ksub) {
                bf16x8 af = *(const bf16x8*)&Pt[g2][col15][ksub * 32 + quad * 8];
#pragma unroll
                for (int ds = 0; ds < 4; ++ds) {
                    bf16x8 bv = *(const bf16x8*)(vb + (size_t)(ds * 16 + col15) * 1024
                                                 + kb64 + ksub * 32 + quad * 8);
                    of[i][ds] = MFMA16(af, bv, of[i][ds]);
                }
            }
        }
        __syncthreads();
    }

#pragma unroll
    for (int i = 0; i < 3; ++i) {
        const int g2 = w * 3 + i;
#pragma unroll
        for (int ds = 0; ds < 4; ++ds) {
            const int colg = g2 * 64 + ds * 16 + col15;
#pragma unroll
            for (int e = 0; e < 4; ++e) {
                const int m = b * 1024 + q0 + quad * 4 + e;
                attn_part[(size_t)ks * 3145728 + (size_t)m * 768 + colg] = of[i][ds][e];
            }
        }
    }
}

// ---------------------------------------------------------------------------
// Combine k-split partials + bp*colsum(V) bias term, convert to bf16.
// ---------------------------------------------------------------------------
__global__ __launch_bounds__(256) void cvt2_k(
    const float* __restrict__ ap, const float* __restrict__ cs,
    const float* __restrict__ bp, unsigned short* __restrict__ abf)
{
    const int idx = blockIdx.x * 256 + threadIdx.x;  // < 3145728
    float v = ap[idx] + ap[idx + 3145728];
    const int col = idx % 768;
    const int b = idx / 786432;
    const int g = col >> 6, d = col & 63;
    v += bp[g] * cs[(b * 12 + g) * 64 + d];
    abf[idx] = f2bf(v);
}

// ---------------------------------------------------------------------------
extern "C" void kernel_launch(void* const* d_in, const int* in_sizes, int n_in,
                              void* d_out, int out_size, void* d_ws, size_t ws_size,
                              hipStream_t stream)
{
    const float* q  = (const float*)d_in[0];
    const float* k  = (const float*)d_in[1];
    const float* v  = (const float*)d_in[2];
    const float* Wq = (const float*)d_in[3];
    const float* bq = (const float*)d_in[4];
    const float* Wl = (const float*)d_in[5];
    const float* bl = (const float*)d_in[6];
    const float* Wp = (const float*)d_in[7];
    const float* bp = (const float*)d_in[8];
    const float* Wf = (const float*)d_in[9];
    const float* bfv = (const float*)d_in[10];

    char* ws = (char*)d_ws;
    unsigned short* qh   = (unsigned short*)(ws);             //  6291456 B
    unsigned short* kh   = (unsigned short*)(ws + 6291456);   //  6291456 B
    unsigned short* vt   = (unsigned short*)(ws + 12582912);  //  6291456 B
    float*          lpart= (float*)(ws + 18874368);           //   393216 B
    float*          csum = (float*)(ws + 19267584);           //    12288 B
    unsigned short* abf  = (unsigned short*)(ws + 19279872);  //  6291456 B
    float*          apart= (float*)(ws + 25571328);           // 25165824 B  (end ~50.7MB)
    float* outp = (float*)d_out;

    hipLaunchKernelGGL(gemm_proj, dim3(32, 12, 3), dim3(256), 0, stream,
                       q, k, v, Wq, bq, qh, kh, vt);
    hipLaunchKernelGGL(colsum_k, dim3(768), dim3(256), 0, stream, vt, csum);
    hipLaunchKernelGGL(attn_pass1, dim3(2, 64, 4), dim3(256), 0, stream,
                       qh, kh, Wl, bl, lpart);
    hipLaunchKernelGGL(attn_pass2, dim3(2, 64, 4), dim3(256), 0, stream,
                       qh, kh, vt, Wl, bl, Wp, lpart, apart);
    hipLaunchKernelGGL(cvt2_k, dim3(12288), dim3(256), 0, stream,
                       apart, csum, bp, abf);
    hipLaunchKernelGGL(gemm_out, dim3(32, 12), dim3(256), 0, stream,
                       abf, Wf, bfv, outp);
}

// Round 4
// 428.420 us; speedup vs baseline: 1.4292x; 1.4292x over previous
//
#include <hip/hip_runtime.h>
#include <hip/hip_bf16.h>

typedef short bf16x8 __attribute__((ext_vector_type(8)));
typedef short bf16x4 __attribute__((ext_vector_type(4)));
typedef float f32x4 __attribute__((ext_vector_type(4)));

#define MFMA16(a,b,c) __builtin_amdgcn_mfma_f32_16x16x32_bf16(a,b,c,0,0,0)

__device__ __forceinline__ unsigned short f2bf(float x){
    unsigned int u = __float_as_uint(x);
    u += 0x7fffu + ((u >> 16) & 1u);
    return (unsigned short)(u >> 16);
}
__device__ __forceinline__ float bf2f(unsigned short h){
    return __uint_as_float(((unsigned int)h) << 16);
}
__device__ __forceinline__ unsigned int f2bf2(float a, float b){
    return ((unsigned int)f2bf(a)) | (((unsigned int)f2bf(b)) << 16);
}

// ---------------------------------------------------------------------------
// GEMM: C[4096,768] = A[4096,768] @ W[768,768]^T + bias
// z = 0,1: q/k -> head-major bf16 [B,H,S,HD]; z = 2: v -> transposed [B,H,HD,S].
// ---------------------------------------------------------------------------
__global__ __launch_bounds__(256) void gemm_proj(
    const float* __restrict__ Aq, const float* __restrict__ Ak, const float* __restrict__ Av,
    const float* __restrict__ W, const float* __restrict__ bias,
    unsigned short* __restrict__ qh, unsigned short* __restrict__ kh,
    unsigned short* __restrict__ vt)
{
    __shared__ __align__(16) unsigned short As[128][56];
    __shared__ __align__(16) unsigned short Bs[64][56];
    const int z = blockIdx.z;
    const float* A = (z == 0) ? Aq : ((z == 1) ? Ak : Av);
    const int m0 = blockIdx.x * 128, n0 = blockIdx.y * 64;
    const int tid = threadIdx.x;
    const int w = tid >> 6, lane = tid & 63, col15 = lane & 15, quad = lane >> 4;

    f32x4 c[2][4];
#pragma unroll
    for (int ms = 0; ms < 2; ++ms)
#pragma unroll
        for (int ns = 0; ns < 4; ++ns) c[ms][ns] = (f32x4){0.f, 0.f, 0.f, 0.f};

    const int arow = tid >> 1, acol = (tid & 1) * 16;
    const int brow = tid >> 2, bcol = (tid & 3) * 8;

    for (int k0 = 0; k0 < 768; k0 += 32) {
        __syncthreads();
        {
            const float* s = A + (size_t)(m0 + arow) * 768 + k0 + acol;
            float4 f0 = ((const float4*)s)[0], f1 = ((const float4*)s)[1];
            float4 f2 = ((const float4*)s)[2], f3 = ((const float4*)s)[3];
            uint4 w0 = make_uint4(f2bf2(f0.x, f0.y), f2bf2(f0.z, f0.w),
                                  f2bf2(f1.x, f1.y), f2bf2(f1.z, f1.w));
            uint4 w1 = make_uint4(f2bf2(f2.x, f2.y), f2bf2(f2.z, f2.w),
                                  f2bf2(f3.x, f3.y), f2bf2(f3.z, f3.w));
            *(uint4*)&As[arow][acol] = w0;
            *(uint4*)&As[arow][acol + 8] = w1;
        }
        {
            const float* s = W + (size_t)(n0 + brow) * 768 + k0 + bcol;
            float4 f0 = ((const float4*)s)[0], f1 = ((const float4*)s)[1];
            uint4 w0 = make_uint4(f2bf2(f0.x, f0.y), f2bf2(f0.z, f0.w),
                                  f2bf2(f1.x, f1.y), f2bf2(f1.z, f1.w));
            *(uint4*)&Bs[brow][bcol] = w0;
        }
        __syncthreads();
        bf16x8 af0 = *(const bf16x8*)&As[w * 32 + col15][quad * 8];
        bf16x8 af1 = *(const bf16x8*)&As[w * 32 + 16 + col15][quad * 8];
        bf16x8 b0 = *(const bf16x8*)&Bs[col15][quad * 8];
        bf16x8 b1 = *(const bf16x8*)&Bs[16 + col15][quad * 8];
        bf16x8 b2 = *(const bf16x8*)&Bs[32 + col15][quad * 8];
        bf16x8 b3 = *(const bf16x8*)&Bs[48 + col15][quad * 8];
        c[0][0] = MFMA16(af0, b0, c[0][0]);
        c[0][1] = MFMA16(af0, b1, c[0][1]);
        c[0][2] = MFMA16(af0, b2, c[0][2]);
        c[0][3] = MFMA16(af0, b3, c[0][3]);
        c[1][0] = MFMA16(af1, b0, c[1][0]);
        c[1][1] = MFMA16(af1, b1, c[1][1]);
        c[1][2] = MFMA16(af1, b2, c[1][2]);
        c[1][3] = MFMA16(af1, b3, c[1][3]);
    }

#pragma unroll
    for (int ms = 0; ms < 2; ++ms)
#pragma unroll
        for (int ns = 0; ns < 4; ++ns) {
            const int colg = n0 + ns * 16 + col15;
            const float bv = bias[colg];
            const int h = colg >> 6, d = colg & 63;
#pragma unroll
            for (int e = 0; e < 4; ++e) {
                const int m = m0 + w * 32 + ms * 16 + quad * 4 + e;
                const int b = m >> 10, sIdx = m & 1023;
                const float val = c[ms][ns][e] + bv;
                if (z == 2)
                    vt[((b * 12 + h) * 64 + d) * 1024 + sIdx] = f2bf(val);
                else {
                    unsigned short* dst = (z == 0) ? qh : kh;
                    dst[((b * 12 + h) * 1024 + sIdx) * 64 + d] = f2bf(val);
                }
            }
        }
}

// ---------------------------------------------------------------------------
// Final GEMM: out[4096,768] = Abf(bf16) @ Wf^T + bf (fp32 out)
// ---------------------------------------------------------------------------
__global__ __launch_bounds__(256) void gemm_out(
    const unsigned short* __restrict__ Abf, const float* __restrict__ W,
    const float* __restrict__ bias, float* __restrict__ out)
{
    __shared__ __align__(16) unsigned short As[128][56];
    __shared__ __align__(16) unsigned short Bs[64][56];
    const int m0 = blockIdx.x * 128, n0 = blockIdx.y * 64;
    const int tid = threadIdx.x;
    const int w = tid >> 6, lane = tid & 63, col15 = lane & 15, quad = lane >> 4;

    f32x4 c[2][4];
#pragma unroll
    for (int ms = 0; ms < 2; ++ms)
#pragma unroll
        for (int ns = 0; ns < 4; ++ns) c[ms][ns] = (f32x4){0.f, 0.f, 0.f, 0.f};

    const int arow = tid >> 1, acol = (tid & 1) * 16;
    const int brow = tid >> 2, bcol = (tid & 3) * 8;

    for (int k0 = 0; k0 < 768; k0 += 32) {
        __syncthreads();
        {
            const unsigned short* s = Abf + (size_t)(m0 + arow) * 768 + k0 + acol;
            *(bf16x8*)&As[arow][acol] = *(const bf16x8*)s;
            *(bf16x8*)&As[arow][acol + 8] = *(const bf16x8*)(s + 8);
        }
        {
            const float* s = W + (size_t)(n0 + brow) * 768 + k0 + bcol;
            float4 f0 = ((const float4*)s)[0], f1 = ((const float4*)s)[1];
            uint4 w0 = make_uint4(f2bf2(f0.x, f0.y), f2bf2(f0.z, f0.w),
                                  f2bf2(f1.x, f1.y), f2bf2(f1.z, f1.w));
            *(uint4*)&Bs[brow][bcol] = w0;
        }
        __syncthreads();
        bf16x8 af0 = *(const bf16x8*)&As[w * 32 + col15][quad * 8];
        bf16x8 af1 = *(const bf16x8*)&As[w * 32 + 16 + col15][quad * 8];
        bf16x8 b0 = *(const bf16x8*)&Bs[col15][quad * 8];
        bf16x8 b1 = *(const bf16x8*)&Bs[16 + col15][quad * 8];
        bf16x8 b2 = *(const bf16x8*)&Bs[32 + col15][quad * 8];
        bf16x8 b3 = *(const bf16x8*)&Bs[48 + col15][quad * 8];
        c[0][0] = MFMA16(af0, b0, c[0][0]);
        c[0][1] = MFMA16(af0, b1, c[0][1]);
        c[0][2] = MFMA16(af0, b2, c[0][2]);
        c[0][3] = MFMA16(af0, b3, c[0][3]);
        c[1][0] = MFMA16(af1, b0, c[1][0]);
        c[1][1] = MFMA16(af1, b1, c[1][1]);
        c[1][2] = MFMA16(af1, b2, c[1][2]);
        c[1][3] = MFMA16(af1, b3, c[1][3]);
    }

#pragma unroll
    for (int ms = 0; ms < 2; ++ms)
#pragma unroll
        for (int ns = 0; ns < 4; ++ns) {
            const int colg = n0 + ns * 16 + col15;
            const float bv = bias[colg];
#pragma unroll
            for (int e = 0; e < 4; ++e) {
                const int m = m0 + w * 32 + ms * 16 + quad * 4 + e;
                out[(size_t)m * 768 + colg] = c[ms][ns][e] + bv;
            }
        }
}

// ---------------------------------------------------------------------------
__global__ __launch_bounds__(256) void colsum_k(
    const unsigned short* __restrict__ vt, float* __restrict__ cs)
{
    const int row = blockIdx.x * 4 + (threadIdx.x >> 6);
    const int lane = threadIdx.x & 63;
    const unsigned short* p = vt + (size_t)row * 1024;
    float s = 0.f;
    for (int i = lane; i < 1024; i += 64) s += bf2f(p[i]);
    s += __shfl_xor(s, 1, 64);  s += __shfl_xor(s, 2, 64);
    s += __shfl_xor(s, 4, 64);  s += __shfl_xor(s, 8, 64);
    s += __shfl_xor(s, 16, 64); s += __shfl_xor(s, 32, 64);
    if (lane == 0) cs[row] = s;
}

// ---------------------------------------------------------------------------
// Head-mix B-fragment (16x16x32 layout): lane holds B[n=col15][k=quad*8+j];
// zero outside the 12x12 real block.
// ---------------------------------------------------------------------------
__device__ __forceinline__ bf16x8 make_mix_frag(const float* __restrict__ Wm,
                                                int col15, int quad, float scale)
{
    bf16x8 f;
#pragma unroll
    for (int j = 0; j < 8; ++j) {
        const int kk = quad * 8 + j;
        float v = (col15 < 12 && kk < 12) ? Wm[col15 * 12 + kk] * scale : 0.f;
        f[j] = (short)f2bf(v);
    }
    return f;
}

// ---------------------------------------------------------------------------
// Attention pass 1: partial row-sums of exp(premixed logits).
// ---------------------------------------------------------------------------
__global__ __launch_bounds__(256) void attn_pass1(
    const unsigned short* __restrict__ qh, const unsigned short* __restrict__ kh,
    const float* __restrict__ Wl, const float* __restrict__ bl,
    float* __restrict__ l_part)
{
    const int ks = blockIdx.x, qt = blockIdx.y, b = blockIdx.z;
    const int tid = threadIdx.x, w = tid >> 6, lane = tid & 63;
    const int col15 = lane & 15, quad = lane >> 4;
    const int q0 = qt * 16;

    __shared__ __align__(16) unsigned short Sm1[4 * 5128];   // per-wave [256 elem][20]
    __shared__ float lred[4][16][16];

    unsigned short* sm = Sm1 + w * 5128;
    // zero pad columns 12..15 of every row ONCE (never read garbage into MFMA:
    // NaN*0 = NaN). Cols 0..11 are overwritten each iter; pads stay zero.
#pragma unroll
    for (int r = 0; r < 4; ++r)
        *(uint2*)&sm[(r * 64 + lane) * 20 + 12] = make_uint2(0u, 0u);

    const bf16x8 wlf = make_mix_frag(Wl, col15, quad, 0.125f);
    const float blv = (col15 < 12) ? bl[col15] : 0.f;
    const f32x4 cinit = (f32x4){blv, blv, blv, blv};

    const unsigned short* qbase = qh + (size_t)(b * 12) * 65536 + (size_t)(q0 + col15) * 64 + quad * 8;
    const unsigned short* kbase0 = kh + (size_t)(b * 12) * 65536 + (size_t)(ks * 512 + w * 16 + col15) * 64 + quad * 8;

    float lsum[16];
#pragma unroll
    for (int t = 0; t < 16; ++t) lsum[t] = 0.f;

    for (int it = 0; it < 8; ++it) {
        const unsigned short* kbase = kbase0 + it * 64 * 64;
#pragma unroll
        for (int hp = 0; hp < 6; ++hp) {
            const int h0 = hp * 2;
            const unsigned short* qp0 = qbase + (size_t)h0 * 65536;
            const unsigned short* kp0 = kbase + (size_t)h0 * 65536;
            f32x4 s0 = (f32x4){0.f, 0.f, 0.f, 0.f};
            f32x4 s1 = (f32x4){0.f, 0.f, 0.f, 0.f};
            s0 = MFMA16(*(const bf16x8*)qp0, *(const bf16x8*)kp0, s0);
            s0 = MFMA16(*(const bf16x8*)(qp0 + 32), *(const bf16x8*)(kp0 + 32), s0);
            s1 = MFMA16(*(const bf16x8*)(qp0 + 65536), *(const bf16x8*)(kp0 + 65536), s1);
            s1 = MFMA16(*(const bf16x8*)(qp0 + 65568), *(const bf16x8*)(kp0 + 65568), s1);
#pragma unroll
            for (int e = 0; e < 4; ++e) {
                const int elem = (quad * 4 + e) * 16 + col15;   // q*16 + kcol
                *(unsigned int*)&sm[elem * 20 + h0] = f2bf2(s0[e], s1[e]);
            }
        }
#pragma unroll
        for (int t = 0; t < 16; ++t) {
            const unsigned short* rp = sm + (t * 16 + col15) * 20 + (quad & 1) * 8;
            bf16x4 lo = *(const bf16x4*)rp;
            bf16x4 hi = *(const bf16x4*)(rp + 4);
            bf16x8 af = {lo[0], lo[1], lo[2], lo[3], hi[0], hi[1], hi[2], hi[3]};
            f32x4 m = MFMA16(af, wlf, cinit);
            float s = __expf(m[0]) + __expf(m[1]) + __expf(m[2]) + __expf(m[3]);
            s += __shfl_xor(s, 16, 64);
            s += __shfl_xor(s, 32, 64);
            lsum[t] += s;
        }
    }

    if (quad == 0) {
#pragma unroll
        for (int t = 0; t < 16; ++t) lred[w][col15][t] = lsum[t];
    }
    __syncthreads();
    if (tid < 192) {
        const int g = tid >> 4, r = tid & 15;
        const float tot = lred[0][g][r] + lred[1][g][r] + lred[2][g][r] + lred[3][g][r];
        l_part[((size_t)(ks * 4 + b) * 12 + g) * 1024 + q0 + r] = tot;
    }
}

// ---------------------------------------------------------------------------
// Attention pass 2: recompute S, MFMA pre-mix, exp*linv, MFMA post-mix,
// PV via MFMA. fp32 partials out (k-split over ks).
// ---------------------------------------------------------------------------
__global__ __launch_bounds__(256) void attn_pass2(
    const unsigned short* __restrict__ qh, const unsigned short* __restrict__ kh,
    const unsigned short* __restrict__ vt,
    const float* __restrict__ Wl, const float* __restrict__ bl,
    const float* __restrict__ Wp,
    const float* __restrict__ l_part, float* __restrict__ attn_part)
{
    const int ks = blockIdx.x, qt = blockIdx.y, b = blockIdx.z;
    const int tid = threadIdx.x, w = tid >> 6, lane = tid & 63;
    const int col15 = lane & 15, quad = lane >> 4;
    const int q0 = qt * 16;

    __shared__ __align__(16) unsigned short Sm1[4 * 5128];   // per-wave [256 elem][20]
    __shared__ __align__(16) unsigned short Sm2[4 * 328];    // per-wave [16 kcol][20]
    __shared__ __align__(16) unsigned short Pt[12][16][72];  // [g2][q][k64]
    __shared__ float linvs[16][16];

    unsigned short* sm = Sm1 + w * 5128;
    unsigned short* sm2 = Sm2 + w * 328;

    // zero Sm1 pad columns 12..15 (see pass1 comment)
#pragma unroll
    for (int r = 0; r < 4; ++r)
        *(uint2*)&sm[(r * 64 + lane) * 20 + 12] = make_uint2(0u, 0u);

    {   // 1/l for this q-tile (pad heads with 1.0)
        const int g = tid >> 4, r = tid & 15;
        float vv = 1.f;
        if (g < 12) {
            const float s = l_part[((size_t)(0 + b) * 12 + g) * 1024 + q0 + r]
                          + l_part[((size_t)(4 + b) * 12 + g) * 1024 + q0 + r];
            vv = 1.f / s;
        }
        linvs[g][r] = vv;
    }

    const bf16x8 wlf = make_mix_frag(Wl, col15, quad, 0.125f);
    const bf16x8 wpf = make_mix_frag(Wp, col15, quad, 1.0f);
    const float blv = (col15 < 12) ? bl[col15] : 0.f;
    const f32x4 cinit = (f32x4){blv, blv, blv, blv};
    const f32x4 zf = (f32x4){0.f, 0.f, 0.f, 0.f};

    __syncthreads();
    float linvv[16];
#pragma unroll
    for (int t = 0; t < 16; ++t) linvv[t] = linvs[col15][t];

    const unsigned short* qbase = qh + (size_t)(b * 12) * 65536 + (size_t)(q0 + col15) * 64 + quad * 8;
    const unsigned short* kbase0 = kh + (size_t)(b * 12) * 65536 + (size_t)(ks * 512 + w * 16 + col15) * 64 + quad * 8;
    const unsigned short* vbase0 = vt + (size_t)(b * 12) * 65536 + (size_t)col15 * 1024 + ks * 512 + quad * 8;

    f32x4 of[3][4];
#pragma unroll
    for (int i = 0; i < 3; ++i)
#pragma unroll
        for (int ds = 0; ds < 4; ++ds) of[i][ds] = zf;

    for (int pt = 0; pt < 8; ++pt) {
        const unsigned short* kbase = kbase0 + pt * 64 * 64;

        // ---- QK -> Sm1 (bf16, elem-major) ----
#pragma unroll
        for (int hp = 0; hp < 6; ++hp) {
            const int h0 = hp * 2;
            const unsigned short* qp0 = qbase + (size_t)h0 * 65536;
            const unsigned short* kp0 = kbase + (size_t)h0 * 65536;
            f32x4 s0 = zf, s1 = zf;
            s0 = MFMA16(*(const bf16x8*)qp0, *(const bf16x8*)kp0, s0);
            s0 = MFMA16(*(const bf16x8*)(qp0 + 32), *(const bf16x8*)(kp0 + 32), s0);
            s1 = MFMA16(*(const bf16x8*)(qp0 + 65536), *(const bf16x8*)(kp0 + 65536), s1);
            s1 = MFMA16(*(const bf16x8*)(qp0 + 65568), *(const bf16x8*)(kp0 + 65568), s1);
#pragma unroll
            for (int e = 0; e < 4; ++e) {
                const int elem = (quad * 4 + e) * 16 + col15;
                *(unsigned int*)&sm[elem * 20 + h0] = f2bf2(s0[e], s1[e]);
            }
        }

        // ---- per q-row tile: premix -> exp*linv -> postmix -> Pt ----
#pragma unroll
        for (int t = 0; t < 16; ++t) {
            const unsigned short* rp = sm + (t * 16 + col15) * 20 + (quad & 1) * 8;
            bf16x4 lo = *(const bf16x4*)rp;
            bf16x4 hi = *(const bf16x4*)(rp + 4);
            bf16x8 af = {lo[0], lo[1], lo[2], lo[3], hi[0], hi[1], hi[2], hi[3]};
            f32x4 m = MFMA16(af, wlf, cinit);
            // p = exp(m)/l   (lane: q=t, kcol=quad*4+e, g=col15)
            const float li = linvv[t];
#pragma unroll
            for (int e = 0; e < 4; ++e) {
                const float p = __expf(m[e]) * li;
                sm2[(quad * 4 + e) * 20 + col15] = f2bf(p);
            }
            const unsigned short* rp2 = sm2 + col15 * 20 + (quad & 1) * 8;
            bf16x4 lo2 = *(const bf16x4*)rp2;
            bf16x4 hi2 = *(const bf16x4*)(rp2 + 4);
            bf16x8 af2 = {lo2[0], lo2[1], lo2[2], lo2[3], hi2[0], hi2[1], hi2[2], hi2[3]};
            f32x4 o = MFMA16(af2, wpf, zf);
            // lane: g2=col15, q=t, kcol=quad*4+e
            if (col15 < 12) {
                uint2 pk = make_uint2(f2bf2(o[0], o[1]), f2bf2(o[2], o[3]));
                *(uint2*)&Pt[col15][t][w * 16 + quad * 4] = pk;
            }
        }
        __syncthreads();

        // ---- PV: wave w handles heads 3w..3w+2 over the 64-key tile ----
#pragma unroll
        for (int i = 0; i < 3; ++i) {
            const int g2 = w * 3 + i;
            const unsigned short* vb = vbase0 + (size_t)g2 * 65536 + pt * 64;
#pragma unroll
            for (int ksub = 0; ksub < 2; ++ksub) {
                bf16x8 afp = *(const bf16x8*)&Pt[g2][col15][ksub * 32 + quad * 8];
#pragma unroll
                for (int ds = 0; ds < 4; ++ds) {
                    bf16x8 bv = *(const bf16x8*)(vb + (size_t)ds * 16384 + ksub * 32);
                    of[i][ds] = MFMA16(afp, bv, of[i][ds]);
                }
            }
        }
        __syncthreads();
    }

#pragma unroll
    for (int i = 0; i < 3; ++i) {
        const int g2 = w * 3 + i;
#pragma unroll
        for (int ds = 0; ds < 4; ++ds) {
            const int colg = g2 * 64 + ds * 16 + col15;
#pragma unroll
            for (int e = 0; e < 4; ++e) {
                const int m = b * 1024 + q0 + quad * 4 + e;
                attn_part[(size_t)ks * 3145728 + (size_t)m * 768 + colg] = of[i][ds][e];
            }
        }
    }
}

// ---------------------------------------------------------------------------
__global__ __launch_bounds__(256) void cvt2_k(
    const float* __restrict__ ap, const float* __restrict__ cs,
    const float* __restrict__ bp, unsigned short* __restrict__ abf)
{
    const int idx = blockIdx.x * 256 + threadIdx.x;
    float v = ap[idx] + ap[idx + 3145728];
    const int col = idx % 768;
    const int b = idx / 786432;
    const int g = col >> 6, d = col & 63;
    v += bp[g] * cs[(b * 12 + g) * 64 + d];
    abf[idx] = f2bf(v);
}

// ---------------------------------------------------------------------------
extern "C" void kernel_launch(void* const* d_in, const int* in_sizes, int n_in,
                              void* d_out, int out_size, void* d_ws, size_t ws_size,
                              hipStream_t stream)
{
    const float* q  = (const float*)d_in[0];
    const float* k  = (const float*)d_in[1];
    const float* v  = (const float*)d_in[2];
    const float* Wq = (const float*)d_in[3];
    const float* bq = (const float*)d_in[4];
    const float* Wl = (const float*)d_in[5];
    const float* bl = (const float*)d_in[6];
    const float* Wp = (const float*)d_in[7];
    const float* bp = (const float*)d_in[8];
    const float* Wf = (const float*)d_in[9];
    const float* bfv = (const float*)d_in[10];

    char* ws = (char*)d_ws;
    unsigned short* qh   = (unsigned short*)(ws);
    unsigned short* kh   = (unsigned short*)(ws + 6291456);
    unsigned short* vt   = (unsigned short*)(ws + 12582912);
    float*          lpart= (float*)(ws + 18874368);
    float*          csum = (float*)(ws + 19267584);
    unsigned short* abf  = (unsigned short*)(ws + 19279872);
    float*          apart= (float*)(ws + 25571328);
    float* outp = (float*)d_out;

    hipLaunchKernelGGL(gemm_proj, dim3(32, 12, 3), dim3(256), 0, stream,
                       q, k, v, Wq, bq, qh, kh, vt);
    hipLaunchKernelGGL(colsum_k, dim3(768), dim3(256), 0, stream, vt, csum);
    hipLaunchKernelGGL(attn_pass1, dim3(2, 64, 4), dim3(256), 0, stream,
                       qh, kh, Wl, bl, lpart);
    hipLaunchKernelGGL(attn_pass2, dim3(2, 64, 4), dim3(256), 0, stream,
                       qh, kh, vt, Wl, bl, Wp, lpart, apart);
    hipLaunchKernelGGL(cvt2_k, dim3(12288), dim3(256), 0, stream,
                       apart, csum, bp, abf);
    hipLaunchKernelGGL(gemm_out, dim3(32, 12), dim3(256), 0, stream,
                       abf, Wf, bfv, outp);
}